// Round 1
// baseline (777.332 us; speedup 1.0000x reference)
//
#include <hip/hip_runtime.h>
#include <math.h>

#define BN_EPS 1e-5f

// ---- workspace layout (in floats) ----
// [0, Y2_ELEMS)                : y2 intermediate (256 x 36 x 436)
// [WST_OFF, WST_OFF+31104)     : WsT transposed weights  [pair=c*24+h][o]
// [CST_OFF, CST_OFF+216)       : folded BN consts: a1,o1,a2,o2,a3,o3 (36 each)
constexpr int Y2_ELEMS = 256 * 36 * 436;
constexpr int WST_OFF  = Y2_ELEMS;
constexpr int CST_OFF  = WST_OFF + 864 * 36;

// ------------------------------------------------------------------
// k0: fold BN consts + transpose Ws
// ------------------------------------------------------------------
__global__ __launch_bounds__(256) void k0_prep(
    const float* __restrict__ Ws,
    const float* __restrict__ bt, const float* __restrict__ g1,
    const float* __restrict__ b1, const float* __restrict__ m1,
    const float* __restrict__ v1,
    const float* __restrict__ bs, const float* __restrict__ g2,
    const float* __restrict__ b2, const float* __restrict__ m2,
    const float* __restrict__ v2,
    const float* __restrict__ bc, const float* __restrict__ g3,
    const float* __restrict__ b3, const float* __restrict__ m3,
    const float* __restrict__ v3,
    float* __restrict__ ws) {
  int idx = blockIdx.x * 256 + threadIdx.x;
  if (idx < 36 * 864) {
    int o = idx / 864, p = idx - o * 864;
    ws[WST_OFF + p * 36 + o] = Ws[idx];
  }
  if (idx < 216) {
    int l = idx / 36, c = idx - l * 36;
    float g, b, m, v, bias;
    if (l < 2)      { g = g1[c]; b = b1[c]; m = m1[c]; v = v1[c]; bias = bt[c]; }
    else if (l < 4) { g = g2[c]; b = b2[c]; m = m2[c]; v = v2[c]; bias = bs[c]; }
    else            { g = g3[c]; b = b3[c]; m = m3[c]; v = v3[c]; bias = bc[c]; }
    float s   = g / sqrtf(v + BN_EPS);
    float off = (bias - m) * s + b;
    ws[CST_OFF + idx] = (l & 1) ? off : s;
  }
}

// ------------------------------------------------------------------
// k1: fused conv1(1x65) + BN/ELU + conv2(36x24 reduce) + BN/ELU -> y2
// grid (28 t-tiles, 256 samples), 512 threads
// ------------------------------------------------------------------
constexpr int T1 = 16;
constexpr int XPITCH = 81;   // 80 cols + 1 pad (bank-conflict-free h rows)
constexpr int Y1P = 20;      // 16 cols + pad, rows 16B-aligned (80B)

__global__ __launch_bounds__(512) void k1_conv12(
    const float* __restrict__ x, const float* __restrict__ Wt,
    const float* __restrict__ ws_ro, float* __restrict__ y2g) {
  __shared__ float sx[24 * XPITCH];
  __shared__ float sWt[36 * 65];
  __shared__ alignas(16) float sy1[864 * Y1P];
  __shared__ float spart[36 * 14 * 16];
  __shared__ float sc[144];

  const int tid  = threadIdx.x;
  const int t0   = blockIdx.x * T1;
  const int b    = blockIdx.y;

  const float* WsT = ws_ro + WST_OFF;
  const float* cst = ws_ro + CST_OFF;

  // ---- stage x window (zero-pad past col 500), Wt, consts ----
  for (int i = tid; i < 24 * 80; i += 512) {
    int h = i / 80, col = i - h * 80;
    float v = 0.f;
    if (t0 + col < 500) v = x[b * 24024 + h * 1001 + 501 + t0 + col];
    sx[h * XPITCH + col] = v;
  }
  for (int i = tid; i < 36 * 65; i += 512) sWt[i] = Wt[i];
  if (tid < 144) sc[tid] = cst[tid];
  __syncthreads();

  // ---- conv1: each thread one (c,h) pair, 16 t's via sliding window ----
  for (int pair = tid; pair < 864; pair += 512) {
    int c = pair / 24, h = pair - c * 24;
    const float* xrow = sx + h * XPITCH;
    const float* wrow = sWt + c * 65;
    float win[16];
#pragma unroll
    for (int j = 0; j < 16; ++j) win[j] = xrow[j];
    float acc[16];
#pragma unroll
    for (int t = 0; t < 16; ++t) acc[t] = 0.f;
#pragma unroll
    for (int k = 0; k < 65; ++k) {
      float w = wrow[k];
#pragma unroll
      for (int t = 0; t < 16; ++t) acc[t] = fmaf(w, win[t], acc[t]);
#pragma unroll
      for (int t = 0; t < 15; ++t) win[t] = win[t + 1];
      win[15] = xrow[k + 16];   // k=64 reads pad col (unused garbage) - safe
    }
    float a1 = sc[c], o1 = sc[36 + c];
    float* yrow = sy1 + pair * Y1P;
#pragma unroll
    for (int t = 0; t < 16; ++t) {
      float v = fmaf(acc[t], a1, o1);
      yrow[t] = v > 0.f ? v : expm1f(v);
    }
  }
  __syncthreads();

  // ---- conv2: 504 threads: (part 0..13) x (o4 0..8, t4 0..3); 4x4 tile ----
  if (tid < 504) {
    int part = tid / 36, r = tid - part * 36;
    int o4 = r >> 2, t4 = r & 3;
    int p0 = (part < 10) ? part * 62 : 620 + (part - 10) * 61;
    int p1 = p0 + ((part < 10) ? 62 : 61);
    float acc[16];
#pragma unroll
    for (int i = 0; i < 16; ++i) acc[i] = 0.f;
    const float* wbase = WsT + o4 * 4;
    const float* ybase = sy1 + t4 * 4;
    for (int p = p0; p < p1; ++p) {
      float4 w  = *reinterpret_cast<const float4*>(wbase + p * 36);
      float4 yv = *reinterpret_cast<const float4*>(ybase + p * Y1P);
      float wa[4] = {w.x, w.y, w.z, w.w};
      float ya[4] = {yv.x, yv.y, yv.z, yv.w};
#pragma unroll
      for (int i = 0; i < 4; ++i)
#pragma unroll
        for (int j = 0; j < 4; ++j)
          acc[i * 4 + j] = fmaf(wa[i], ya[j], acc[i * 4 + j]);
    }
    float* pb = spart + (r * 14 + part) * 16;
#pragma unroll
    for (int i = 0; i < 16; ++i) pb[i] = acc[i];
  }
  __syncthreads();

  // ---- reduce 14 partials + BN2/ELU + store y2 ----
  for (int u = tid; u < 576; u += 512) {
    int o = u >> 4, t = u & 15;
    int r = (o >> 2) * 4 + (t >> 2);
    int i = (o & 3) * 4 + (t & 3);
    const float* pb = spart + r * 14 * 16 + i;
    float s = 0.f;
#pragma unroll
    for (int part = 0; part < 14; ++part) s += pb[part * 16];
    float v = fmaf(s, sc[72 + o], sc[108 + o]);
    v = v > 0.f ? v : expm1f(v);
    if (t0 + t < 436) y2g[(b * 36 + o) * 436 + t0 + t] = v;
  }
}

// ------------------------------------------------------------------
// k2: per-sample pool3 + conv3(1x15) + BN/ELU + pool15 + FC + residual
// grid 256 (one block per sample), 256 threads
// ------------------------------------------------------------------
__global__ __launch_bounds__(256) void k2_tail(
    const float* __restrict__ y2g, const float* __restrict__ ws_ro,
    const float* __restrict__ Wc, const float* __restrict__ Wf,
    const float* __restrict__ bfv, float* __restrict__ out) {
  __shared__ float sy2[36 * 436];
  __shared__ float sp[36 * 145 + 8];   // +8 pad: window overreads stay in-bounds
  __shared__ float sy3[36 * 131];
  __shared__ float sf[288];
  const int tid = threadIdx.x;
  const int b   = blockIdx.x;
  const float* cst = ws_ro + CST_OFF;

  for (int i = tid; i < 36 * 436; i += 256) sy2[i] = y2g[b * (36 * 436) + i];
  __syncthreads();

  // pool3: 36 x 145
  for (int i = tid; i < 36 * 145; i += 256) {
    int o = i / 145, u = i - o * 145;
    const float* r = sy2 + o * 436 + u * 3;
    sp[i] = (r[0] + r[1] + r[2]) * (1.f / 3.f);
  }
  __syncthreads();

  // conv3: units = 36 o2 x 17 t3-blocks of 8
  for (int u = tid; u < 36 * 17; u += 256) {
    int o2 = u / 17, tb = u - o2 * 17;
    int t3_0 = tb * 8;
    float acc[8];
#pragma unroll
    for (int t = 0; t < 8; ++t) acc[t] = 0.f;
    for (int o = 0; o < 36; ++o) {
      const float* prow = sp + o * 145 + t3_0;
      float win[22];
#pragma unroll
      for (int j = 0; j < 22; ++j) win[j] = prow[j];
      const float* wrow = Wc + (o2 * 36 + o) * 15;
#pragma unroll
      for (int k = 0; k < 15; ++k) {
        float w = wrow[k];
#pragma unroll
        for (int t = 0; t < 8; ++t) acc[t] = fmaf(w, win[k + t], acc[t]);
      }
    }
    float a3 = cst[144 + o2], o3c = cst[180 + o2];
#pragma unroll
    for (int t = 0; t < 8; ++t) {
      int t3 = t3_0 + t;
      if (t3 < 131) {
        float v = fmaf(acc[t], a3, o3c);
        sy3[o2 * 131 + t3] = v > 0.f ? v : expm1f(v);
      }
    }
  }
  __syncthreads();

  // pool15 -> f (288)
  for (int u = tid; u < 288; u += 256) {
    int o2 = u >> 3, j = u & 7;
    const float* r = sy3 + o2 * 131 + j * 15;
    float s = 0.f;
#pragma unroll
    for (int k = 0; k < 15; ++k) s += r[k];
    sf[u] = s * (1.f / 15.f);
  }
  __syncthreads();

  // FC + residual + /501
  for (int n = tid; n < 288; n += 256) {
    float acc = bfv[n] + sf[n];
#pragma unroll 4
    for (int m = 0; m < 288; ++m) acc = fmaf(sf[m], Wf[m * 288 + n], acc);
    out[b * 288 + n] = acc * (1.f / 501.f);
  }
}

// ------------------------------------------------------------------
extern "C" void kernel_launch(void* const* d_in, const int* in_sizes, int n_in,
                              void* d_out, int out_size, void* d_ws, size_t ws_size,
                              hipStream_t stream) {
  const float* x  = (const float*)d_in[0];
  const float* Wt = (const float*)d_in[1];
  const float* bt = (const float*)d_in[2];
  const float* g1 = (const float*)d_in[3];
  const float* b1 = (const float*)d_in[4];
  const float* m1 = (const float*)d_in[5];
  const float* v1 = (const float*)d_in[6];
  const float* Ws = (const float*)d_in[7];
  const float* bs = (const float*)d_in[8];
  const float* g2 = (const float*)d_in[9];
  const float* b2 = (const float*)d_in[10];
  const float* m2 = (const float*)d_in[11];
  const float* v2 = (const float*)d_in[12];
  const float* Wc = (const float*)d_in[13];
  const float* bc = (const float*)d_in[14];
  const float* g3 = (const float*)d_in[15];
  const float* b3 = (const float*)d_in[16];
  const float* m3 = (const float*)d_in[17];
  const float* v3 = (const float*)d_in[18];
  const float* Wf = (const float*)d_in[19];
  const float* bf = (const float*)d_in[20];

  float* ws  = (float*)d_ws;
  float* out = (float*)d_out;

  k0_prep<<<dim3(122), dim3(256), 0, stream>>>(Ws, bt, g1, b1, m1, v1,
                                               bs, g2, b2, m2, v2,
                                               bc, g3, b3, m3, v3, ws);
  k1_conv12<<<dim3(28, 256), dim3(512), 0, stream>>>(x, Wt, ws, ws);
  k2_tail<<<dim3(256), dim3(256), 0, stream>>>(ws, ws, Wc, Wf, bf, out);
}